// Round 1
// baseline (1492.595 us; speedup 1.0000x reference)
//
#include <hip/hip_runtime.h>

#define NEGF (-1e30f)

typedef __attribute__((ext_vector_type(8))) short short8;
typedef __attribute__((ext_vector_type(4))) float float4v;

__device__ __forceinline__ short f2bf(float f) {
  union { float f; unsigned u; } v; v.f = f;
  unsigned r = v.u + 0x7fffu + ((v.u >> 16) & 1u);  // RNE truncate to bf16
  return (short)(r >> 16);
}
__device__ __forceinline__ float sigf(float x) { return 1.0f / (1.0f + __expf(-x)); }
__device__ __forceinline__ float tanhfast(float x) { return 1.0f - 2.0f / (__expf(2.0f * x) + 1.0f); }

// ---------------------------------------------------------------------------
// prep: stage Wcat = [Wh1;Wh2] (256x640 f32) into bf16 MFMA B-fragment layout.
// frag id = nt*8+kk (nt=0..39, kk=0..7). Lane holds B[k][n] with
// k = kk*32 + (lane>>4)*8 + j, n = nt*16 + (lane&15); 16B per lane.
__global__ void prep_w_kernel(const float* __restrict__ Wh1, const float* __restrict__ Wh2,
                              short* __restrict__ wsW) {
  int t = blockIdx.x * 256 + threadIdx.x;   // 0..20479
  int lane = t & 63;
  int frag = t >> 6;                        // 0..319
  int nt = frag >> 3, kk = frag & 7;
  int n  = nt * 16 + (lane & 15);
  int kb = kk * 32 + (lane >> 4) * 8;
  short8 v;
#pragma unroll
  for (int j = 0; j < 8; ++j) {
    int k = kb + j;
    float w = (k < 128) ? Wh1[k * 640 + n] : Wh2[(k - 128) * 640 + n];
    v[j] = f2bf(w);
  }
  ((short8*)wsW)[frag * 64 + lane] = v;
}

// ---------------------------------------------------------------------------
// MDLSTM wavefront kernel: one block per batch, 8 waves.
// Wave g owns gate-feature columns j0=16g..16g+15 for all 5 gates
// (N-tiles {q*8+g}), both M-tiles -> epilogue is fully in-register.
__global__ __launch_bounds__(512, 2)
void mdlstm_kernel(const float* __restrict__ X, const short* __restrict__ wsW,
                   const float* __restrict__ Wx, const float* __restrict__ bias,
                   float* __restrict__ feat) {
  __shared__ __align__(16) short h_buf[32][136];  // stride 272B: 16B-aligned, 2-way bank alias (free)
  __shared__ float c_buf[32][132];
  __shared__ float x_cur[32];

  const int b    = blockIdx.x;
  const int tid  = threadIdx.x;
  const int lane = tid & 63;
  const int g    = tid >> 6;       // wave 0..7
  const int col  = lane & 15;
  const int quad = lane >> 4;
  const int jj   = g * 16 + col;   // h-feature column this lane owns

  // zero-init state: gives h=c=0 boundary at w=0 / h=0 (row m untouched until diag d==m)
  for (int i = tid; i < 32 * 136; i += 512) ((short*)h_buf)[i] = 0;
  for (int i = tid; i < 32 * 132; i += 512) ((float*)c_buf)[i] = 0.0f;

  float wx[5], bg[5];
#pragma unroll
  for (int q = 0; q < 5; ++q) {
    wx[q] = Wx[q * 128 + jj];
    bg[q] = bias[q * 128 + jj];
  }
  const float* Xb = X + b * (256 * 32);
  float* featb = feat + b * (256 * 128);
  const short8* W8 = (const short8*)wsW;
  __syncthreads();

  for (int d = 0; d < 287; ++d) {
    // x for cell (h=m, w=d-m): X[b][w][m]
    if (tid < 32) {
      int w = d - tid;
      x_cur[tid] = (w >= 0 && w < 256) ? Xb[w * 32 + tid] : 0.0f;
    }
    float4v acc[5][2];
#pragma unroll
    for (int q = 0; q < 5; ++q) {
      acc[q][0] = (float4v){0.f, 0.f, 0.f, 0.f};
      acc[q][1] = (float4v){0.f, 0.f, 0.f, 0.f};
    }
    // K-loop: A = [h_left | h_up] read straight out of h_buf
#pragma unroll
    for (int kk = 0; kk < 8; ++kk) {
      const int kb = kk * 32 + quad * 8;
      short8 af[2];
#pragma unroll
      for (int mt = 0; mt < 2; ++mt) {
        int m = mt * 16 + col;
        int row = (kb < 128) ? m : (m - 1);  // k<128: left neighbor (row m); else up (row m-1)
        int cc  = kb & 127;
        if (row >= 0) af[mt] = *(const short8*)&h_buf[row][cc];
        else          af[mt] = (short8){0, 0, 0, 0, 0, 0, 0, 0};
      }
#pragma unroll
      for (int q = 0; q < 5; ++q) {
        short8 bf = W8[((q * 8 + g) * 8 + kk) * 64 + lane];
        acc[q][0] = __builtin_amdgcn_mfma_f32_16x16x32_bf16(af[0], bf, acc[q][0], 0, 0, 0);
        acc[q][1] = __builtin_amdgcn_mfma_f32_16x16x32_bf16(af[1], bf, acc[q][1], 0, 0, 0);
      }
    }
    __syncthreads();  // h_buf reads done before epilogue overwrites

    // hoist ALL c reads before any c writes (intra-wave rows m / m-1 overlap)
    float cl[2][4], cu[2][4];
#pragma unroll
    for (int mt = 0; mt < 2; ++mt)
#pragma unroll
      for (int r = 0; r < 4; ++r) {
        int m = mt * 16 + quad * 4 + r;
        cl[mt][r] = c_buf[m][jj];
        cu[mt][r] = (m > 0) ? c_buf[m - 1][jj] : 0.0f;
      }
#pragma unroll
    for (int mt = 0; mt < 2; ++mt)
#pragma unroll
      for (int r = 0; r < 4; ++r) {
        int m = mt * 16 + quad * 4 + r;   // C/D layout: row = quad*4 + reg
        int w = d - m;
        float xm = x_cur[m];
        float zi = acc[0][mt][r] + xm * wx[0] + bg[0];
        float zg = acc[1][mt][r] + xm * wx[1] + bg[1];
        float z1 = acc[2][mt][r] + xm * wx[2] + bg[2];
        float z2 = acc[3][mt][r] + xm * wx[3] + bg[3];
        float zo = acc[4][mt][r] + xm * wx[4] + bg[4];
        float c = sigf(z1) * cl[mt][r] + sigf(z2) * cu[mt][r] + sigf(zi) * tanhfast(zg);
        float h = sigf(zo) * tanhfast(c);
        if (w >= 0 && w < 256) {          // invalid cells: preserve zero-init state
          c_buf[m][jj] = c;
          h_buf[m][jj] = f2bf(h);
          featb[w * 128 + jj] += h;       // height collapse; unique (w,jj) per lane
        }
      }
    __syncthreads();  // state visible before next diagonal's reads
  }
}

// ---------------------------------------------------------------------------
// logits = feat @ W_fc + b_fc, then log_softmax -> logp [32][256][101]
__global__ __launch_bounds__(256)
void logits_kernel(const float* __restrict__ feat, const float* __restrict__ Wfc,
                   const float* __restrict__ bfc, float* __restrict__ logp) {
  __shared__ float sW[128 * 101];
  __shared__ float sF[8][128];
  __shared__ float sL[8][104];
  __shared__ float sLse[8];
  const int tid = threadIdx.x;
  const int b  = blockIdx.x >> 5;
  const int t0 = (blockIdx.x & 31) * 8;

  for (int i = tid; i < 128 * 101; i += 256) sW[i] = Wfc[i];
  for (int i = tid; i < 8 * 128; i += 256)
    sF[i >> 7][i & 127] = feat[(b * 256 + t0 + (i >> 7)) * 128 + (i & 127)];
  __syncthreads();
  for (int idx = tid; idx < 8 * 101; idx += 256) {
    int tr = idx / 101, v = idx - tr * 101;
    float s = bfc[v];
#pragma unroll 4
    for (int k = 0; k < 128; ++k) s += sF[tr][k] * sW[k * 101 + v];
    sL[tr][v] = s;
  }
  __syncthreads();
  if (tid < 8) {
    float m = NEGF;
    for (int v = 0; v < 101; ++v) m = fmaxf(m, sL[tid][v]);
    float su = 0.0f;
    for (int v = 0; v < 101; ++v) su += __expf(sL[tid][v] - m);
    sLse[tid] = m + __logf(su);
  }
  __syncthreads();
  for (int idx = tid; idx < 8 * 101; idx += 256) {
    int tr = idx / 101, v = idx - tr * 101;
    logp[(b * 256 + t0 + tr) * 101 + v] = sL[tr][v] - sLse[tr];
  }
}

// ---------------------------------------------------------------------------
// CTC forward: one wave per batch. Lane l holds alpha[s=l]; lane 63 also s=64.
__global__ __launch_bounds__(64)
void ctc_kernel(const float* __restrict__ logp, const int* __restrict__ y,
                float* __restrict__ out) {
  const int b = blockIdx.x;
  const int l = threadIdx.x;
  const float* lpb = logp + b * 256 * 101;
  const int* yb = y + b * 32;
  int lab = (l & 1) ? yb[l >> 1] : 100;                 // ext[s]: odd->label, even->blank
  bool skip = (l & 1) && (l >= 3) && (yb[l >> 1] != yb[(l >> 1) - 1]);

  float a   = (l == 0) ? lpb[100] : ((l == 1) ? lpb[lab] : NEGF);
  float a64 = NEGF;                                      // alpha[64] (valid on lane 63)
  for (int t = 1; t < 256; ++t) {
    const float* lpt = lpb + t * 101;
    float lpl = lpt[lab];
    float lpblank = lpt[100];
    float am1 = __shfl_up(a, 1); if (l == 0) am1 = NEGF;
    float am2 = __shfl_up(a, 2); if (l < 2 || !skip) am2 = NEGF;
    float m3 = fmaxf(a, fmaxf(am1, am2));
    float na = m3 + __logf(__expf(a - m3) + __expf(am1 - m3) + __expf(am2 - m3)) + lpl;
    float m2 = fmaxf(a64, a);                            // s=64: lse(alpha64, alpha63)
    float na64 = m2 + __logf(__expf(a64 - m2) + __expf(a - m2)) + lpblank;
    a = na;
    a64 = na64;
  }
  float A63 = __shfl(a, 63);
  float A64 = __shfl(a64, 63);
  if (l == 0) {
    float m = fmaxf(A63, A64);
    out[b] = -(m + __logf(__expf(A63 - m) + __expf(A64 - m)));
  }
}

// ---------------------------------------------------------------------------
extern "C" void kernel_launch(void* const* d_in, const int* in_sizes, int n_in,
                              void* d_out, int out_size, void* d_ws, size_t ws_size,
                              hipStream_t stream) {
  const float* X   = (const float*)d_in[0];
  const int*   y   = (const int*)d_in[1];
  const float* Wx  = (const float*)d_in[2];
  const float* Wh1 = (const float*)d_in[3];
  const float* Wh2 = (const float*)d_in[4];
  const float* bi  = (const float*)d_in[5];
  const float* Wfc = (const float*)d_in[6];
  const float* bfc = (const float*)d_in[7];
  float* out = (float*)d_out;

  char* ws = (char*)d_ws;
  short* wsW  = (short*)(ws);              // 327,680 B staged weights
  float* feat = (float*)(ws + 0x50000);    // 4 MiB feat accumulator
  float* logp = (float*)(ws + 0x450000);   // 3.31 MB log-probs

  hipMemsetAsync(feat, 0, 32 * 256 * 128 * sizeof(float), stream);  // ws is 0xAA-poisoned
  prep_w_kernel<<<80, 256, 0, stream>>>(Wh1, Wh2, wsW);
  mdlstm_kernel<<<32, 512, 0, stream>>>(X, wsW, Wx, bi, feat);
  logits_kernel<<<1024, 256, 0, stream>>>(feat, Wfc, bfc, logp);
  ctc_kernel<<<32, 64, 0, stream>>>(logp, y, out);
}

// Round 2
// 1262.925 us; speedup vs baseline: 1.1819x; 1.1819x over previous
//
#include <hip/hip_runtime.h>

#define NEGF (-1e30f)

typedef __attribute__((ext_vector_type(8))) short short8;
typedef __attribute__((ext_vector_type(4))) float float4v;

template <bool V> struct BC { static constexpr bool value = V; };

__device__ __forceinline__ short f2bf(float f) {
  union { float f; unsigned u; } v; v.f = f;
  unsigned r = v.u + 0x7fffu + ((v.u >> 16) & 1u);  // RNE truncate to bf16
  return (short)(r >> 16);
}
__device__ __forceinline__ float fastrcp(float x) { return __builtin_amdgcn_rcpf(x); }
__device__ __forceinline__ float sigf(float x) { return fastrcp(1.0f + __expf(-x)); }
__device__ __forceinline__ float tanhfast(float x) { return 1.0f - 2.0f * fastrcp(__expf(2.0f * x) + 1.0f); }

// ---------------------------------------------------------------------------
// prep: stage Wcat = [Wh1;Wh2] (256x640 f32) into bf16 MFMA B-fragment layout.
// frag id = nt*8+kk (nt=0..39, kk=0..7). Lane holds B[k][n] with
// k = kk*32 + (lane>>4)*8 + j, n = nt*16 + (lane&15); 16B per lane.
__global__ void prep_w_kernel(const float* __restrict__ Wh1, const float* __restrict__ Wh2,
                              short* __restrict__ wsW) {
  int t = blockIdx.x * 256 + threadIdx.x;   // 0..20479
  int lane = t & 63;
  int frag = t >> 6;                        // 0..319
  int nt = frag >> 3, kk = frag & 7;
  int n  = nt * 16 + (lane & 15);
  int kb = kk * 32 + (lane >> 4) * 8;
  short8 v;
#pragma unroll
  for (int j = 0; j < 8; ++j) {
    int k = kb + j;
    float w = (k < 128) ? Wh1[k * 640 + n] : Wh2[(k - 128) * 640 + n];
    v[j] = f2bf(w);
  }
  ((short8*)wsW)[frag * 64 + lane] = v;
}

// ---------------------------------------------------------------------------
// MDLSTM wavefront kernel: one block per batch, 8 waves, 1 barrier/diagonal.
// Wave g owns gate-feature columns j0=16g..16g+15 for all 5 gates; weights
// for those columns (40 B-frags = 160 VGPR) are pinned in registers.
__global__ __launch_bounds__(512, 2)
void mdlstm_kernel(const float* __restrict__ X, const short* __restrict__ wsW,
                   const float* __restrict__ Wx, const float* __restrict__ bias,
                   float* __restrict__ feat) {
  __shared__ __align__(16) short h_buf[2][32][136];  // double-buffered h (bf16)
  __shared__ float c_buf[32][132];                   // single-buffered c (wave-local cols)
  __shared__ float Xs[256 * 32];                     // whole X[b] staged once

  const int b    = blockIdx.x;
  const int tid  = threadIdx.x;
  const int lane = tid & 63;
  const int g    = tid >> 6;       // wave 0..7
  const int col  = lane & 15;
  const int quad = lane >> 4;
  const int jj   = g * 16 + col;   // h-feature column this lane owns

  // zero-init both h buffers + c: boundary h=c=0 for w<0 / h<0
  for (int i = tid; i < 2 * 32 * 136; i += 512) ((short*)h_buf)[i] = 0;
  for (int i = tid; i < 32 * 132; i += 512) ((float*)c_buf)[i] = 0.0f;
  {
    const float4* Xb4 = (const float4*)(X + b * 8192);
    for (int i = tid; i < 2048; i += 512) ((float4*)Xs)[i] = Xb4[i];
  }

  float wx[5], bg[5];
#pragma unroll
  for (int q = 0; q < 5; ++q) {
    wx[q] = Wx[q * 128 + jj];
    bg[q] = bias[q * 128 + jj];
  }
  // pin this wave's weight fragments in registers (loaded once)
  short8 wgt[5][8];
  {
    const short8* W8 = (const short8*)wsW;
#pragma unroll
    for (int q = 0; q < 5; ++q)
#pragma unroll
      for (int kk = 0; kk < 8; ++kk)
        wgt[q][kk] = W8[((q * 8 + g) * 8 + kk) * 64 + lane];
  }
  float* featb = feat + b * (256 * 128);
  __syncthreads();

  auto step = [&](int d, auto c0, auto c1) {
    constexpr bool DO0 = decltype(c0)::value;   // rows 0..15 active
    constexpr bool DO1 = decltype(c1)::value;   // rows 16..31 active
    const short(*hrd)[136] = h_buf[(d + 1) & 1];  // written at d-1
    short(*hwr)[136] = h_buf[d & 1];

    float4v acc[5][2];
#pragma unroll
    for (int q = 0; q < 5; ++q) {
      if (DO0) acc[q][0] = (float4v){0.f, 0.f, 0.f, 0.f};
      if (DO1) acc[q][1] = (float4v){0.f, 0.f, 0.f, 0.f};
    }
    const short8 z8 = (short8){0, 0, 0, 0, 0, 0, 0, 0};
#pragma unroll
    for (int kk = 0; kk < 8; ++kk) {
      const int kb = kk * 32 + quad * 8;
      const int up = (kb >= 128) ? 1 : 0;   // k<128: left neighbor; k>=128: up
      const int cc = kb & 127;
      short8 a0, a1;
      if (DO0) {
        int row = col - up;
        a0 = (row >= 0) ? *(const short8*)&hrd[row][cc] : z8;
      }
      if (DO1) {
        int row = 16 + col - up;
        a1 = *(const short8*)&hrd[row][cc];
      }
#pragma unroll
      for (int q = 0; q < 5; ++q) {
        if (DO0) acc[q][0] = __builtin_amdgcn_mfma_f32_16x16x32_bf16(a0, wgt[q][kk], acc[q][0], 0, 0, 0);
        if (DO1) acc[q][1] = __builtin_amdgcn_mfma_f32_16x16x32_bf16(a1, wgt[q][kk], acc[q][1], 0, 0, 0);
      }
    }

    // ---- epilogue: hoist ALL c reads (old values) + feat loads, then compute ----
    float cl[2][4], cu0[2], fo[2][4];
#pragma unroll
    for (int mt = 0; mt < 2; ++mt) {
      if ((mt == 0 && !DO0) || (mt == 1 && !DO1)) continue;
      const int m0 = mt * 16 + quad * 4;
#pragma unroll
      for (int r = 0; r < 4; ++r) cl[mt][r] = c_buf[m0 + r][jj];
      cu0[mt] = (m0 > 0) ? c_buf[m0 - 1][jj] : 0.0f;
#pragma unroll
      for (int r = 0; r < 4; ++r) {
        int w = d - (m0 + r);
        fo[mt][r] = (w >= 0 && w < 256) ? featb[w * 128 + jj] : 0.0f;  // early L2 load
      }
    }
#pragma unroll
    for (int mt = 0; mt < 2; ++mt) {
      if ((mt == 0 && !DO0) || (mt == 1 && !DO1)) continue;
      const int m0 = mt * 16 + quad * 4;
#pragma unroll
      for (int r = 0; r < 4; ++r) {
        const int m = m0 + r;          // C/D layout: row = quad*4 + reg
        const int w = d - m;
        if (w >= 0 && w < 256) {
          float c_up = (r == 0) ? cu0[mt] : cl[mt][r - 1];
          float xm = Xs[w * 32 + m];
          float zi = acc[0][mt][r] + xm * wx[0] + bg[0];
          float zg = acc[1][mt][r] + xm * wx[1] + bg[1];
          float z1 = acc[2][mt][r] + xm * wx[2] + bg[2];
          float z2 = acc[3][mt][r] + xm * wx[3] + bg[3];
          float zo = acc[4][mt][r] + xm * wx[4] + bg[4];
          float c = sigf(z1) * cl[mt][r] + sigf(z2) * c_up + sigf(zi) * tanhfast(zg);
          float h = sigf(zo) * tanhfast(c);
          c_buf[m][jj] = c;
          hwr[m][jj] = f2bf(h);
          featb[w * 128 + jj] = fo[mt][r] + h;   // unique (w,jj) per lane per diag
        }
      }
    }
  };

  BC<true> T; BC<false> F;
  for (int d = 0; d < 16; ++d)    { step(d, T, F); __syncthreads(); }
  for (int d = 16; d < 271; ++d)  { step(d, T, T); __syncthreads(); }
  for (int d = 271; d < 287; ++d) { step(d, F, T); __syncthreads(); }
}

// ---------------------------------------------------------------------------
// logits = feat @ W_fc + b_fc, then log_softmax -> logp [32][256][101]
__global__ __launch_bounds__(256)
void logits_kernel(const float* __restrict__ feat, const float* __restrict__ Wfc,
                   const float* __restrict__ bfc, float* __restrict__ logp) {
  __shared__ float sW[128 * 101];
  __shared__ float sF[8][128];
  __shared__ float sL[8][104];
  __shared__ float sLse[8];
  const int tid = threadIdx.x;
  const int b  = blockIdx.x >> 5;
  const int t0 = (blockIdx.x & 31) * 8;

  for (int i = tid; i < 128 * 101; i += 256) sW[i] = Wfc[i];
  for (int i = tid; i < 8 * 128; i += 256)
    sF[i >> 7][i & 127] = feat[(b * 256 + t0 + (i >> 7)) * 128 + (i & 127)];
  __syncthreads();
  for (int idx = tid; idx < 8 * 101; idx += 256) {
    int tr = idx / 101, v = idx - tr * 101;
    float s = bfc[v];
#pragma unroll 4
    for (int k = 0; k < 128; ++k) s += sF[tr][k] * sW[k * 101 + v];
    sL[tr][v] = s;
  }
  __syncthreads();
  if (tid < 8) {
    float m = NEGF;
    for (int v = 0; v < 101; ++v) m = fmaxf(m, sL[tid][v]);
    float su = 0.0f;
    for (int v = 0; v < 101; ++v) su += __expf(sL[tid][v] - m);
    sLse[tid] = m + __logf(su);
  }
  __syncthreads();
  for (int idx = tid; idx < 8 * 101; idx += 256) {
    int tr = idx / 101, v = idx - tr * 101;
    logp[(b * 256 + t0 + tr) * 101 + v] = sL[tr][v] - sLse[tr];
  }
}

// ---------------------------------------------------------------------------
// CTC forward: one wave per batch. Lane l holds alpha[s=l]; lane 63 also s=64.
__global__ __launch_bounds__(64)
void ctc_kernel(const float* __restrict__ logp, const int* __restrict__ y,
                float* __restrict__ out) {
  const int b = blockIdx.x;
  const int l = threadIdx.x;
  const float* lpb = logp + b * 256 * 101;
  const int* yb = y + b * 32;
  int lab = (l & 1) ? yb[l >> 1] : 100;                 // ext[s]: odd->label, even->blank
  bool skip = (l & 1) && (l >= 3) && (yb[l >> 1] != yb[(l >> 1) - 1]);

  float a   = (l == 0) ? lpb[100] : ((l == 1) ? lpb[lab] : NEGF);
  float a64 = NEGF;                                      // alpha[64] (valid on lane 63)
  for (int t = 1; t < 256; ++t) {
    const float* lpt = lpb + t * 101;
    float lpl = lpt[lab];
    float lpblank = lpt[100];
    float am1 = __shfl_up(a, 1); if (l == 0) am1 = NEGF;
    float am2 = __shfl_up(a, 2); if (l < 2 || !skip) am2 = NEGF;
    float m3 = fmaxf(a, fmaxf(am1, am2));
    float na = m3 + __logf(__expf(a - m3) + __expf(am1 - m3) + __expf(am2 - m3)) + lpl;
    float m2 = fmaxf(a64, a);                            // s=64: lse(alpha64, alpha63)
    float na64 = m2 + __logf(__expf(a64 - m2) + __expf(a - m2)) + lpblank;
    a = na;
    a64 = na64;
  }
  float A63 = __shfl(a, 63);
  float A64 = __shfl(a64, 63);
  if (l == 0) {
    float m = fmaxf(A63, A64);
    out[b] = -(m + __logf(__expf(A63 - m) + __expf(A64 - m)));
  }
}

// ---------------------------------------------------------------------------
extern "C" void kernel_launch(void* const* d_in, const int* in_sizes, int n_in,
                              void* d_out, int out_size, void* d_ws, size_t ws_size,
                              hipStream_t stream) {
  const float* X   = (const float*)d_in[0];
  const int*   y   = (const int*)d_in[1];
  const float* Wx  = (const float*)d_in[2];
  const float* Wh1 = (const float*)d_in[3];
  const float* Wh2 = (const float*)d_in[4];
  const float* bi  = (const float*)d_in[5];
  const float* Wfc = (const float*)d_in[6];
  const float* bfc = (const float*)d_in[7];
  float* out = (float*)d_out;

  char* ws = (char*)d_ws;
  short* wsW  = (short*)(ws);              // 327,680 B staged weights
  float* feat = (float*)(ws + 0x50000);    // 4 MiB feat accumulator
  float* logp = (float*)(ws + 0x450000);   // 3.31 MB log-probs

  hipMemsetAsync(feat, 0, 32 * 256 * 128 * sizeof(float), stream);  // ws is 0xAA-poisoned
  prep_w_kernel<<<80, 256, 0, stream>>>(Wh1, Wh2, wsW);
  mdlstm_kernel<<<32, 512, 0, stream>>>(X, wsW, Wx, bi, feat);
  logits_kernel<<<1024, 256, 0, stream>>>(feat, Wfc, bfc, logp);
  ctc_kernel<<<32, 64, 0, stream>>>(logp, y, out);
}